// Round 14
// baseline (4175.658 us; speedup 1.0000x reference)
//
#include <hip/hip_runtime.h>
#include <math.h>

#define HID  1024
#define SEQ  512
#define NB   64
#define DIN0 512

using short8 = __attribute__((ext_vector_type(8))) short;
using f32x4  = __attribute__((ext_vector_type(4))) float;

__device__ __forceinline__ unsigned short f2bf(float f) {
    unsigned int u = __float_as_uint(f);
    u += 0x7fffu + ((u >> 16) & 1u);          // round-to-nearest-even
    return (unsigned short)(u >> 16);
}
__device__ __forceinline__ float sigm_(float x) { return 1.0f / (1.0f + __expf(-x)); }
__device__ __forceinline__ float tanh_(float x) {
    float ax = fabsf(x);
    float e = __expf(-2.0f * ax);
    float t = (1.0f - e) / (1.0f + e);
    return copysignf(t, x);
}

// ---- no-wait load issue (vmcnt counted manually in the K-loop) ----
__device__ __forceinline__ void ld_coh(short8* a, const unsigned short* p) {   // device-coherent
    asm volatile("global_load_dwordx4 %0, %1, off sc0 sc1" : "=&v"(*a) : "v"(p) : "memory");
}
__device__ __forceinline__ void ld_pln(short8* a, const unsigned short* p) {   // cached
    asm volatile("global_load_dwordx4 %0, %1, off" : "=&v"(*a) : "v"(p) : "memory");
}
__device__ __forceinline__ void st_coh_u16(unsigned short* p, unsigned short v) {
    asm volatile("global_store_short %0, %1, off sc0 sc1" :: "v"(p), "v"((unsigned)v) : "memory");
}

// Persistent fused 2-layer GRU, dataflow-synced (NO global barrier).
// 256 blocks x 512 thr (8 waves = 2/SIMD), 1 block/CU, [32b x 16j] tiles.
// hb0 = h0/out0 ring-4 (slot st&3); hb1 = h1 ping-pong (read st&1, write ^1).
// Coherence: hb via sc0sc1 write-through + bypass loads; no cache fences.
// Sync: per-block monotonic flags. L0(beta,jsl) waits fL0(beta,*)>=i and
// fL1(beta,*)>=i-2 (ring anti-overwrite); L1 waits fL0>=i and fL1>=i.
// L0 (K=1536, lighter) runs ~2 intervals ahead; critical path = L1 chain.
// K-loop: all NK load groups issued upfront (R13-proven, no ring reuse).
template<int LAYER>
__device__ __forceinline__ void gru_loop(
    const unsigned short* __restrict__ xb,
    const unsigned short* __restrict__ Wi, const unsigned short* __restrict__ Wh,
    const float* __restrict__ bi, const float* __restrict__ bh_,
    const float* __restrict__ h0f,
    unsigned short* __restrict__ hb0, unsigned short* __restrict__ hb1,
    float* out,                                  // d_out: [64][512][1024] ++ hn[2][64][1024]
    unsigned* __restrict__ bar, int bid, float (*lds)[2][16][68])
{
    constexpr int Din = LAYER ? HID : DIN0;
    constexpr int K   = Din + HID;
    constexpr int Kq  = K / 8;               // per-wave K range: 192 or 256
    constexpr int NK  = Kq / 32;             // 6 or 8 K-steps per wave

    const int q    = bid & 127;
    const int jsl  = q >> 1;                 // j-slice 0..63
    const int j0   = jsl << 4;               // 16-col j slice
    const int beta = q & 1;                  // batch half
    const int b0   = beta << 5;
    const int tid  = threadIdx.x;
    const int l    = tid & 63;
    const int w    = tid >> 6;               // wave id 0..7 = K-eighth
    const int c    = l & 15;                 // frag col / A row
    const int kg   = l >> 4;                 // k subgroup
    const int kq0  = w * Kq;

    const unsigned* pA = bar + beta * 64;        // L0(beta) flags, idx = jsl
    const unsigned* pB = bar + 128 + beta * 64;  // L1(beta) flags
    unsigned* myflag = (unsigned*)(LAYER ? pB : pA) + jsl;

    // ---- one-time: weight B-frags into registers (72 or 96 VGPRs) ----
    short8 Br[NK], Bz[NK], Bn[NK];
#pragma unroll
    for (int s = 0; s < NK; ++s) {
        const int k0 = kq0 + s * 32 + kg * 8;
        const unsigned short *pr, *pz, *pn;
        if (k0 < Din) {
            pr = Wi + (long)(j0 + c) * Din + k0;
            pz = Wi + (long)(HID + j0 + c) * Din + k0;
            pn = Wi + (long)(2 * HID + j0 + c) * Din + k0;
        } else {
            pr = Wh + (long)(j0 + c) * HID + (k0 - Din);
            pz = Wh + (long)(HID + j0 + c) * HID + (k0 - Din);
            pn = Wh + (long)(2 * HID + j0 + c) * HID + (k0 - Din);
        }
        Br[s] = *(const short8*)pr;
        Bz[s] = *(const short8*)pz;
        Bn[s] = *(const short8*)pn;
    }

    const long hrow0 = (long)(b0 + c) * HID;        // A rows for m=0 / m=1
    const long hrow1 = (long)(b0 + 16 + c) * HID;
    const long xrow0 = (long)(b0 + c) * SEQ * DIN0;
    const long xrow1 = (long)(b0 + 16 + c) * SEQ * DIN0;

    // ---- combine-phase invariants: thread -> (batch b0+cb, col j0+jc) ----
    const int cb  = tid >> 4;                // 0..31
    const int jc  = tid & 15;
    const int cm  = cb >> 4, cbr = cb & 15;
    const int j   = j0 + jc;
    const int bgl = b0 + cb;
    const float bir = bi[j], biz = bi[HID + j], bin = bi[2 * HID + j];
    const float bhr = bh_[j], bhz = bh_[HID + j], bhn = bh_[2 * HID + j];
    float hreg = h0f[LAYER * 65536 + bgl * 1024 + j];   // h state in register

    for (int i = 0; i <= SEQ; ++i) {
        if (LAYER == 0 && i == SEQ) break;   // L0 has nothing at the last interval

        // ---- dependency wait: wave 0 polls exactly the producer sets ----
        if (tid < 64) {
            const int thrA = i;                       // need L0 peers done interval i-1
            const int thrB = LAYER ? i : (i - 2);     // L1 peers; L0: ring-4 slack
            for (;;) {
                int a = (int)__hip_atomic_load(pA + tid, __ATOMIC_RELAXED, __HIP_MEMORY_SCOPE_AGENT);
                int b = (int)__hip_atomic_load(pB + tid, __ATOMIC_RELAXED, __HIP_MEMORY_SCOPE_AGENT);
                if (__all((a >= thrA) & (b >= thrB))) break;
                __builtin_amdgcn_s_sleep(2);
            }
        }
        __syncthreads();

        const int st = LAYER ? (i - 1) : i;
        if (st >= 0 && st < SEQ) {
            // ring/ping-pong slots
            const unsigned short* Alo = hb0 + (long)(st & 3) * 65536;            // L1: out0(st)
            const unsigned short* Ahi = LAYER ? hb1 + (long)(st & 1) * 65536     // h1(st-1)
                                              : hb0 + (long)((st + 3) & 3) * 65536; // h0(st-1)
            const unsigned short* xp0 = xb + xrow0 + (long)st * DIN0;
            const unsigned short* xp1 = xb + xrow1 + (long)st * DIN0;

            f32x4 acc_r[2], acc_z[2], acc_nx[2], acc_nh[2];
#pragma unroll
            for (int m = 0; m < 2; ++m) {
                acc_r[m] = (f32x4){0.f, 0.f, 0.f, 0.f};
                acc_z[m] = (f32x4){0.f, 0.f, 0.f, 0.f};
                acc_nx[m] = (f32x4){0.f, 0.f, 0.f, 0.f};
                acc_nh[m] = (f32x4){0.f, 0.f, 0.f, 0.f};
            }

            short8 abuf[NK][2];   // one slot per K-group, written exactly once

#define ISSUE(g) do {                                                          \
    const int kk_ = kq0 + (g) * 32 + kg * 8;                                   \
    const bool lo_ = (kq0 + (g) * 32) < Din;                                   \
    if (LAYER == 0) {                                                          \
        if (lo_) { ld_pln(&abuf[g][0], xp0 + kk_);                             \
                   ld_pln(&abuf[g][1], xp1 + kk_); }                           \
        else     { ld_coh(&abuf[g][0], Ahi + hrow0 + (kk_ - Din));             \
                   ld_coh(&abuf[g][1], Ahi + hrow1 + (kk_ - Din)); }           \
    } else {                                                                   \
        const unsigned short* bse_ = lo_ ? (Alo + kk_) : (Ahi + (kk_ - HID));  \
        ld_coh(&abuf[g][0], bse_ + hrow0);                                     \
        ld_coh(&abuf[g][1], bse_ + hrow1);                                     \
    } } while (0)

#define WSTEP(s, W) do {                                                                               \
    asm volatile("s_waitcnt vmcnt(" #W ")" ::: "memory");                                              \
    __builtin_amdgcn_sched_barrier(0);                                                                 \
    const bool lo_ = (kq0 + (s) * 32) < Din;                                                           \
    acc_r[0] = __builtin_amdgcn_mfma_f32_16x16x32_bf16(abuf[s][0], Br[s], acc_r[0], 0, 0, 0);          \
    acc_r[1] = __builtin_amdgcn_mfma_f32_16x16x32_bf16(abuf[s][1], Br[s], acc_r[1], 0, 0, 0);          \
    acc_z[0] = __builtin_amdgcn_mfma_f32_16x16x32_bf16(abuf[s][0], Bz[s], acc_z[0], 0, 0, 0);          \
    acc_z[1] = __builtin_amdgcn_mfma_f32_16x16x32_bf16(abuf[s][1], Bz[s], acc_z[1], 0, 0, 0);          \
    if (lo_) {                                                                                         \
        acc_nx[0] = __builtin_amdgcn_mfma_f32_16x16x32_bf16(abuf[s][0], Bn[s], acc_nx[0], 0, 0, 0);    \
        acc_nx[1] = __builtin_amdgcn_mfma_f32_16x16x32_bf16(abuf[s][1], Bn[s], acc_nx[1], 0, 0, 0);    \
    } else {                                                                                           \
        acc_nh[0] = __builtin_amdgcn_mfma_f32_16x16x32_bf16(abuf[s][0], Bn[s], acc_nh[0], 0, 0, 0);    \
        acc_nh[1] = __builtin_amdgcn_mfma_f32_16x16x32_bf16(abuf[s][1], Bn[s], acc_nh[1], 0, 0, 0);    \
    } } while (0)

            if constexpr (NK == 8) {
                ISSUE(0); ISSUE(1); ISSUE(2); ISSUE(3);
                ISSUE(4); ISSUE(5); ISSUE(6); ISSUE(7);     // 16 loads in flight
                WSTEP(0, 14); WSTEP(1, 12); WSTEP(2, 10); WSTEP(3, 8);
                WSTEP(4, 6);  WSTEP(5, 4);  WSTEP(6, 2);  WSTEP(7, 0);
            } else {
                ISSUE(0); ISSUE(1); ISSUE(2);
                ISSUE(3); ISSUE(4); ISSUE(5);               // 12 loads in flight
                WSTEP(0, 10); WSTEP(1, 8); WSTEP(2, 6);
                WSTEP(3, 4);  WSTEP(4, 2); WSTEP(5, 0);
            }
#undef ISSUE
#undef WSTEP

            // ---- single-phase reduce: every wave writes packed gate quads ----
#pragma unroll
            for (int m = 0; m < 2; ++m)
#pragma unroll
                for (int v = 0; v < 4; ++v) {
                    f32x4 pk = { acc_r[m][v], acc_z[m][v], acc_nx[m][v], acc_nh[m][v] };
                    *(f32x4*)&lds[w][m][kg * 4 + v][c * 4] = pk;   // C/D: row=(l>>4)*4+v, col=l&15
                }
            __syncthreads();

            // ---- combine 8 wave-partials + pointwise: 1 item/thread ----
            float rr = 0.f, zz = 0.f, nx = 0.f, nh = 0.f;
#pragma unroll
            for (int ww = 0; ww < 8; ++ww) {
                f32x4 g = *(const f32x4*)&lds[ww][cm][cbr][jc * 4];
                rr += g[0]; zz += g[1]; nx += g[2]; nh += g[3];
            }
            const float r = sigm_(rr + bir + bhr);
            const float z = sigm_(zz + biz + bhz);
            const float n = tanh_((nx + bin) + r * (nh + bhn));
            const float hnew = (1.f - z) * hreg + z * n;
            hreg = hnew;
            unsigned short* stw = LAYER ? hb1 + (long)((st & 1) ^ 1) * 65536
                                        : hb0 + (long)(st & 3) * 65536;
            st_coh_u16(stw + (long)bgl * HID + j, f2bf(hnew));   // device-visible h
            if (LAYER) out[((long)bgl * SEQ + st) * HID + j] = hnew;
            if (st == SEQ - 1)                                   // h_n tail of d_out
                out[(long)NB * SEQ * HID + LAYER * 65536 + bgl * 1024 + j] = hnew;
        }

        if (i == SEQ) break;   // L1 final interval: output stored, done

        // ---- publish: all stores acked at L3, then bump own flag ----
        asm volatile("s_waitcnt vmcnt(0)" ::: "memory");
        __syncthreads();
        if (tid == 0)
            __hip_atomic_store(myflag, (unsigned)(i + 1), __ATOMIC_RELAXED, __HIP_MEMORY_SCOPE_AGENT);
    }
}

__global__ __launch_bounds__(512, 2) void gru_persist(
    const unsigned short* __restrict__ xb,
    const unsigned short* __restrict__ W0i, const unsigned short* __restrict__ W0h,
    const unsigned short* __restrict__ W1i, const unsigned short* __restrict__ W1h,
    const float* __restrict__ bi0, const float* __restrict__ bh0,
    const float* __restrict__ bi1, const float* __restrict__ bh1,
    const float* __restrict__ h0f,
    unsigned short* __restrict__ hb0, unsigned short* __restrict__ hb1,
    float* out, unsigned* __restrict__ bar)
{
    __shared__ float lds[8][2][16][68];   // [wave][m][row][16 cols x 4 gates + pad]
    const int bid = blockIdx.x;
    if (bid < 128) gru_loop<0>(xb, W0i, W0h, bi0, bh0, h0f, hb0, hb1, out, bar, bid, lds);
    else           gru_loop<1>(xb, W1i, W1h, bi1, bh1, h0f, hb0, hb1, out, bar, bid, lds);
}

__global__ __launch_bounds__(256) void cvt_bf16(const float* __restrict__ src,
                                                unsigned short* __restrict__ dst, int n4) {
    int i = blockIdx.x * 256 + threadIdx.x;
    if (i >= n4) return;
    float4 f = *(const float4*)(src + 4L * i);
    unsigned long long u =  (unsigned long long)f2bf(f.x)
                         | ((unsigned long long)f2bf(f.y) << 16)
                         | ((unsigned long long)f2bf(f.z) << 32)
                         | ((unsigned long long)f2bf(f.w) << 48);
    *(unsigned long long*)(dst + 4L * i) = u;
}

// h0(-1) -> hb0 ring slot 3 (st=0 reads slot (0+3)&3 = 3);
// h1(-1) -> hb1 slot 0 (st=0 reads slot st&1 = 0).
__global__ __launch_bounds__(256) void init_h(const float* __restrict__ h0,
                                              unsigned short* __restrict__ hb0,
                                              unsigned short* __restrict__ hb1) {
    int i = blockIdx.x * 256 + threadIdx.x;          // 2*64*1024 threads
    float v = h0[i];
    if (i < 65536) hb0[3L * 65536 + i] = f2bf(v);
    else           hb1[(long)(i - 65536)] = f2bf(v);
}

extern "C" void kernel_launch(void* const* d_in, const int* in_sizes, int n_in,
                              void* d_out, int out_size, void* d_ws, size_t ws_size,
                              hipStream_t stream) {
    const float* x    = (const float*)d_in[0];
    const float* h0   = (const float*)d_in[1];
    const float* Wih0 = (const float*)d_in[2];
    const float* Whh0 = (const float*)d_in[3];
    const float* bih0 = (const float*)d_in[4];
    const float* bhh0 = (const float*)d_in[5];
    const float* Wih1 = (const float*)d_in[6];
    const float* Whh1 = (const float*)d_in[7];
    const float* bih1 = (const float*)d_in[8];
    const float* bhh1 = (const float*)d_in[9];

    float* out = (float*)d_out;                      // [64][512][1024] ++ hn[2][64][1024]

    // ws layout (~54 MiB):
    unsigned short* W0i = (unsigned short*)d_ws;             // [3072][512]
    unsigned short* W0h = W0i + 3072L * 512;                 // [3072][1024]
    unsigned short* W1i = W0h + 3072L * 1024;
    unsigned short* W1h = W1i + 3072L * 1024;
    unsigned short* hb0 = W1h + 3072L * 1024;                // ring-4 x [64][1024] bf16
    unsigned short* hb1 = hb0 + 4L * 65536;                  // ping-pong-2
    unsigned*       bar = (unsigned*)(hb1 + 2L * 65536);     // fL0(128) + fL1(128)
    unsigned short* xb  = (unsigned short*)(bar + 512);      // [64][512][512] bf16

    // flags MUST be zero each call (ws is poisoned before timing)
    hipMemsetAsync(bar, 0, 2048, stream);

    cvt_bf16<<<(3072 * 512 / 4  + 255) / 256, 256, 0, stream>>>(Wih0, W0i, 3072 * 512 / 4);
    cvt_bf16<<<(3072 * 1024 / 4 + 255) / 256, 256, 0, stream>>>(Whh0, W0h, 3072 * 1024 / 4);
    cvt_bf16<<<(3072 * 1024 / 4 + 255) / 256, 256, 0, stream>>>(Wih1, W1i, 3072 * 1024 / 4);
    cvt_bf16<<<(3072 * 1024 / 4 + 255) / 256, 256, 0, stream>>>(Whh1, W1h, 3072 * 1024 / 4);
    cvt_bf16<<<(NB * SEQ * DIN0 / 4 + 255) / 256, 256, 0, stream>>>(x, xb, NB * SEQ * DIN0 / 4);
    init_h<<<512, 256, 0, stream>>>(h0, hb0, hb1);

    gru_persist<<<256, 512, 0, stream>>>(xb, W0i, W0h, W1i, W1h,
                                         bih0, bhh0, bih1, bhh1,
                                         h0, hb0, hb1, out, bar);
}

// Round 16
// 3284.679 us; speedup vs baseline: 1.2713x; 1.2713x over previous
//
#include <hip/hip_runtime.h>
#include <math.h>

#define HID  1024
#define SEQ  512
#define NB   64
#define DIN0 512

using short8 = __attribute__((ext_vector_type(8))) short;
using f32x4  = __attribute__((ext_vector_type(4))) float;

__device__ __forceinline__ unsigned short f2bf(float f) {
    unsigned int u = __float_as_uint(f);
    u += 0x7fffu + ((u >> 16) & 1u);          // round-to-nearest-even
    return (unsigned short)(u >> 16);
}
__device__ __forceinline__ float sigm_(float x) { return 1.0f / (1.0f + __expf(-x)); }
__device__ __forceinline__ float tanh_(float x) {
    float ax = fabsf(x);
    float e = __expf(-2.0f * ax);
    float t = (1.0f - e) / (1.0f + e);
    return copysignf(t, x);
}

// ---- no-wait load issue (vmcnt counted manually in the K-loop) ----
__device__ __forceinline__ void ld_coh(short8* a, const unsigned short* p) {   // device-coherent
    asm volatile("global_load_dwordx4 %0, %1, off sc0 sc1" : "=&v"(*a) : "v"(p) : "memory");
}
__device__ __forceinline__ void ld_pln(short8* a, const unsigned short* p) {   // cached
    asm volatile("global_load_dwordx4 %0, %1, off" : "=&v"(*a) : "v"(p) : "memory");
}
__device__ __forceinline__ void st_coh_u16(unsigned short* p, unsigned short v) {
    asm volatile("global_store_short %0, %1, off sc0 sc1" :: "v"(p), "v"((unsigned)v) : "memory");
}

// Persistent fused 2-layer GRU. 256 blocks x 512 thr (8 waves = 2/SIMD),
// 1 block/CU. Block = [32 batches x 16 j-cols]. Coherence: hb via sc0sc1
// write-through + bypass loads; NO cache fences, NO atomics. Weights in VGPRs
// (K-eighth per wave). Barrier: per-block flag stores + block-0 checker.
// R9-proven configuration (session best: 3.29 ms) — final submission.
template<int LAYER>
__device__ __forceinline__ void gru_loop(
    const unsigned short* __restrict__ xb,
    const unsigned short* __restrict__ Wi, const unsigned short* __restrict__ Wh,
    const float* __restrict__ bi, const float* __restrict__ bh_,
    float* __restrict__ hf, unsigned short* __restrict__ hb,
    float* __restrict__ out, unsigned* __restrict__ bar,
    int bid, float (*lds)[2][16][68])
{
    constexpr int Din = LAYER ? HID : DIN0;
    constexpr int K   = Din + HID;
    constexpr int Kq  = K / 8;               // per-wave K range: 192 or 256
    constexpr int NK  = Kq / 32;             // 6 or 8 K-steps per wave

    const int q   = bid & 127;
    const int j0  = (q >> 1) << 4;           // 16-col j slice
    const int b0  = (q & 1) << 5;            // batch half: 0 or 32
    const int tid = threadIdx.x;
    const int l   = tid & 63;
    const int w   = tid >> 6;                // wave id 0..7 = K-eighth
    const int c   = l & 15;                  // frag col / A row
    const int kg  = l >> 4;                  // k subgroup
    const int kq0 = w * Kq;

    unsigned* gens  = bar;                   // 8 gen lines, stride 16 u32
    unsigned* flags = bar + 128;             // 256 per-block flags

    // ---- one-time: weight B-frags into registers (72 or 96 VGPRs) ----
    short8 Br[NK], Bz[NK], Bn[NK];
#pragma unroll
    for (int s = 0; s < NK; ++s) {
        const int k0 = kq0 + s * 32 + kg * 8;
        const unsigned short *pr, *pz, *pn;
        if (k0 < Din) {
            pr = Wi + (long)(j0 + c) * Din + k0;
            pz = Wi + (long)(HID + j0 + c) * Din + k0;
            pn = Wi + (long)(2 * HID + j0 + c) * Din + k0;
        } else {
            pr = Wh + (long)(j0 + c) * HID + (k0 - Din);
            pz = Wh + (long)(HID + j0 + c) * HID + (k0 - Din);
            pn = Wh + (long)(2 * HID + j0 + c) * HID + (k0 - Din);
        }
        Br[s] = *(const short8*)pr;
        Bz[s] = *(const short8*)pz;
        Bn[s] = *(const short8*)pn;
    }

    const long hrow0 = (long)(b0 + c) * HID;        // A rows for m=0 / m=1
    const long hrow1 = (long)(b0 + 16 + c) * HID;
    const long xrow0 = (long)(b0 + c) * SEQ * DIN0;
    const long xrow1 = (long)(b0 + 16 + c) * SEQ * DIN0;

    // ---- combine-phase invariants: thread -> (batch b0+cb, col j0+jc) ----
    const int cb  = tid >> 4;                // 0..31
    const int jc  = tid & 15;
    const int cm  = cb >> 4, cbr = cb & 15;
    const int j   = j0 + jc;
    const float bir = bi[j], biz = bi[HID + j], bin = bi[2 * HID + j];
    const float bhr = bh_[j], bhz = bh_[HID + j], bhn = bh_[2 * HID + j];

    for (int i = 0; i <= SEQ; ++i) {
        const int st = LAYER ? (i - 1) : i;
        if (st >= 0 && st < SEQ) {
            const int rp = st & 1, wp = rp ^ 1;
            const unsigned short* Alo = hb + (long)(0 * 2 + wp) * NB * HID;      // L1: out0(st)
            const unsigned short* Ahi = hb + (long)(LAYER * 2 + rp) * NB * HID;  // own h(st-1)
            const unsigned short* xp0 = xb + xrow0 + (long)st * DIN0;
            const unsigned short* xp1 = xb + xrow1 + (long)st * DIN0;

            f32x4 acc_r[2], acc_z[2], acc_nx[2], acc_nh[2];
#pragma unroll
            for (int m = 0; m < 2; ++m) {
                acc_r[m] = (f32x4){0.f, 0.f, 0.f, 0.f};
                acc_z[m] = (f32x4){0.f, 0.f, 0.f, 0.f};
                acc_nx[m] = (f32x4){0.f, 0.f, 0.f, 0.f};
                acc_nh[m] = (f32x4){0.f, 0.f, 0.f, 0.f};
            }

            short8 abuf[4][2];   // 4-deep ring x 2 m-tiles

#define ISSUE(g) do {                                                          \
    const int kk_ = kq0 + (g) * 32 + kg * 8;                                   \
    const bool lo_ = (kq0 + (g) * 32) < Din;                                   \
    if (LAYER == 0) {                                                          \
        if (lo_) { ld_pln(&abuf[(g) & 3][0], xp0 + kk_);                       \
                   ld_pln(&abuf[(g) & 3][1], xp1 + kk_); }                     \
        else     { ld_coh(&abuf[(g) & 3][0], Ahi + hrow0 + (kk_ - Din));       \
                   ld_coh(&abuf[(g) & 3][1], Ahi + hrow1 + (kk_ - Din)); }     \
    } else {                                                                   \
        const unsigned short* bse_ = lo_ ? (Alo + kk_) : (Ahi + (kk_ - HID));  \
        ld_coh(&abuf[(g) & 3][0], bse_ + hrow0);                               \
        ld_coh(&abuf[(g) & 3][1], bse_ + hrow1);                               \
    } } while (0)

#define MSTEP(s) do {                                                                                  \
    const bool lo_ = (kq0 + (s) * 32) < Din;                                                           \
    acc_r[0] = __builtin_amdgcn_mfma_f32_16x16x32_bf16(abuf[(s) & 3][0], Br[s], acc_r[0], 0, 0, 0);    \
    acc_r[1] = __builtin_amdgcn_mfma_f32_16x16x32_bf16(abuf[(s) & 3][1], Br[s], acc_r[1], 0, 0, 0);    \
    acc_z[0] = __builtin_amdgcn_mfma_f32_16x16x32_bf16(abuf[(s) & 3][0], Bz[s], acc_z[0], 0, 0, 0);    \
    acc_z[1] = __builtin_amdgcn_mfma_f32_16x16x32_bf16(abuf[(s) & 3][1], Bz[s], acc_z[1], 0, 0, 0);    \
    if (lo_) {                                                                                         \
        acc_nx[0] = __builtin_amdgcn_mfma_f32_16x16x32_bf16(abuf[(s) & 3][0], Bn[s], acc_nx[0], 0, 0, 0); \
        acc_nx[1] = __builtin_amdgcn_mfma_f32_16x16x32_bf16(abuf[(s) & 3][1], Bn[s], acc_nx[1], 0, 0, 0); \
    } else {                                                                                           \
        acc_nh[0] = __builtin_amdgcn_mfma_f32_16x16x32_bf16(abuf[(s) & 3][0], Bn[s], acc_nh[0], 0, 0, 0); \
        acc_nh[1] = __builtin_amdgcn_mfma_f32_16x16x32_bf16(abuf[(s) & 3][1], Bn[s], acc_nh[1], 0, 0, 0); \
    } } while (0)

#define KSTEP(s, W) do {                                                       \
    if ((s) + 3 < NK) ISSUE((s) + 3);                                          \
    asm volatile("s_waitcnt vmcnt(" #W ")" ::: "memory");                      \
    __builtin_amdgcn_sched_barrier(0);                                         \
    MSTEP(s); } while (0)

            ISSUE(0); ISSUE(1); ISSUE(2);
            if constexpr (NK == 8) {
                KSTEP(0, 6); KSTEP(1, 6); KSTEP(2, 6); KSTEP(3, 6);
                KSTEP(4, 6); KSTEP(5, 4); KSTEP(6, 2); KSTEP(7, 0);
            } else {
                KSTEP(0, 6); KSTEP(1, 6); KSTEP(2, 6);
                KSTEP(3, 4); KSTEP(4, 2); KSTEP(5, 0);
            }
#undef ISSUE
#undef MSTEP
#undef KSTEP

            // ---- single-phase reduce: every wave writes packed gate quads ----
#pragma unroll
            for (int m = 0; m < 2; ++m)
#pragma unroll
                for (int v = 0; v < 4; ++v) {
                    f32x4 pk = { acc_r[m][v], acc_z[m][v], acc_nx[m][v], acc_nh[m][v] };
                    *(f32x4*)&lds[w][m][kg * 4 + v][c * 4] = pk;   // C/D: row=(l>>4)*4+v, col=l&15
                }
            __syncthreads();

            // ---- combine 8 wave-partials + pointwise: 1 item/thread ----
            float rr = 0.f, zz = 0.f, nx = 0.f, nh = 0.f;
#pragma unroll
            for (int ww = 0; ww < 8; ++ww) {
                f32x4 g = *(const f32x4*)&lds[ww][cm][cbr][jc * 4];
                rr += g[0]; zz += g[1]; nx += g[2]; nh += g[3];
            }
            const float r = sigm_(rr + bir + bhr);
            const float z = sigm_(zz + biz + bhz);
            const float n = tanh_((nx + bin) + r * (nh + bhn));
            const int bgl = b0 + cb;                       // global batch
            const long pofs = ((long)(LAYER * 2 + rp) * NB + bgl) * HID + j;
            const long nofs = ((long)(LAYER * 2 + wp) * NB + bgl) * HID + j;
            const float hp = hf[pofs];                     // block-private, cached
            const float hnew = (1.f - z) * hp + z * n;
            hf[nofs] = hnew;
            st_coh_u16(hb + nofs, f2bf(hnew));             // device-visible h state
            if (LAYER) out[((long)bgl * SEQ + st) * HID + j] = hnew;
        }

        if (i == SEQ) break;   // kernel-end sync covers the trailing memcpys

        // ---- grid barrier: flag stores + block-0 checker, zero atomics ----
        asm volatile("s_waitcnt vmcnt(0)" ::: "memory");   // hb write-through acked at L3
        __syncthreads();                                   // all threads' stores acked
        const unsigned tgt = (unsigned)(i + 1);
        if (tid == 0)
            __hip_atomic_store(flags + bid, tgt, __ATOMIC_RELAXED, __HIP_MEMORY_SCOPE_AGENT);
        if (bid == 0) {
            if (tid < 64) {
                bool ok;
                do {
                    unsigned f0 = __hip_atomic_load(flags + tid,       __ATOMIC_RELAXED, __HIP_MEMORY_SCOPE_AGENT);
                    unsigned f1 = __hip_atomic_load(flags + 64 + tid,  __ATOMIC_RELAXED, __HIP_MEMORY_SCOPE_AGENT);
                    unsigned f2 = __hip_atomic_load(flags + 128 + tid, __ATOMIC_RELAXED, __HIP_MEMORY_SCOPE_AGENT);
                    unsigned f3 = __hip_atomic_load(flags + 192 + tid, __ATOMIC_RELAXED, __HIP_MEMORY_SCOPE_AGENT);
                    ok = (f0 >= tgt) & (f1 >= tgt) & (f2 >= tgt) & (f3 >= tgt);
                } while (!__all(ok));
                if (tid < 8)
                    __hip_atomic_store(gens + tid * 16, tgt, __ATOMIC_RELAXED, __HIP_MEMORY_SCOPE_AGENT);
            }
            __syncthreads();
        } else {
            if (tid == 0) {
                while (__hip_atomic_load(gens + (bid & 7) * 16, __ATOMIC_RELAXED, __HIP_MEMORY_SCOPE_AGENT) < tgt)
                    __builtin_amdgcn_s_sleep(2);
            }
            __syncthreads();
        }
    }
}

__global__ __launch_bounds__(512, 2) void gru_persist(
    const unsigned short* __restrict__ xb,
    const unsigned short* __restrict__ W0i, const unsigned short* __restrict__ W0h,
    const unsigned short* __restrict__ W1i, const unsigned short* __restrict__ W1h,
    const float* __restrict__ bi0, const float* __restrict__ bh0,
    const float* __restrict__ bi1, const float* __restrict__ bh1,
    float* __restrict__ hf, unsigned short* __restrict__ hb,
    float* __restrict__ out, unsigned* __restrict__ bar)
{
    __shared__ float lds[8][2][16][68];   // [wave][m][row][16 cols x 4 gates + pad]
    const int bid = blockIdx.x;
    if (bid < 128) gru_loop<0>(xb, W0i, W0h, bi0, bh0, hf, hb, out, bar, bid, lds);
    else           gru_loop<1>(xb, W1i, W1h, bi1, bh1, hf, hb, out, bar, bid, lds);
}

__global__ __launch_bounds__(256) void cvt_bf16(const float* __restrict__ src,
                                                unsigned short* __restrict__ dst, int n4) {
    int i = blockIdx.x * 256 + threadIdx.x;
    if (i >= n4) return;
    float4 f = *(const float4*)(src + 4L * i);
    unsigned long long u =  (unsigned long long)f2bf(f.x)
                         | ((unsigned long long)f2bf(f.y) << 16)
                         | ((unsigned long long)f2bf(f.z) << 32)
                         | ((unsigned long long)f2bf(f.w) << 48);
    *(unsigned long long*)(dst + 4L * i) = u;
}

__global__ __launch_bounds__(256) void init_h(const float* __restrict__ h0,
                                              float* __restrict__ hf,
                                              unsigned short* __restrict__ hb) {
    int i = blockIdx.x * 256 + threadIdx.x;          // 2*64*1024 threads
    int layer = i >> 16, idx = i & 65535;
    float v = h0[i];
    hf[(long)(layer * 2 + 0) * 65536 + idx] = v;     // parity 0
    hb[(long)(layer * 2 + 0) * 65536 + idx] = f2bf(v);
}

extern "C" void kernel_launch(void* const* d_in, const int* in_sizes, int n_in,
                              void* d_out, int out_size, void* d_ws, size_t ws_size,
                              hipStream_t stream) {
    const float* x    = (const float*)d_in[0];
    const float* h0   = (const float*)d_in[1];
    const float* Wih0 = (const float*)d_in[2];
    const float* Whh0 = (const float*)d_in[3];
    const float* bih0 = (const float*)d_in[4];
    const float* bhh0 = (const float*)d_in[5];
    const float* Wih1 = (const float*)d_in[6];
    const float* Whh1 = (const float*)d_in[7];
    const float* bih1 = (const float*)d_in[8];
    const float* bhh1 = (const float*)d_in[9];

    float* out   = (float*)d_out;                    // [64][512][1024]
    float* hnout = out + (long)NB * SEQ * HID;       // [2][64][1024]

    // ws layout (~56 MiB):
    unsigned short* W0i = (unsigned short*)d_ws;             // [3072][512]
    unsigned short* W0h = W0i + 3072L * 512;                 // [3072][1024]
    unsigned short* W1i = W0h + 3072L * 1024;
    unsigned short* W1h = W1i + 3072L * 1024;
    float*          hf  = (float*)(W1h + 3072L * 1024);      // [2][2][64][1024] f32
    unsigned short* hb  = (unsigned short*)(hf + 4L * 65536);
    unsigned*       bar = (unsigned*)(hb + 4L * 65536);      // gens(8x16) + flags(256)
    unsigned short* xb  = (unsigned short*)(bar + 512);      // [64][512][512] bf16

    // gen lines + flags MUST be zero each call (ws is poisoned before timing)
    hipMemsetAsync(bar, 0, 2048, stream);

    cvt_bf16<<<(3072 * 512 / 4  + 255) / 256, 256, 0, stream>>>(Wih0, W0i, 3072 * 512 / 4);
    cvt_bf16<<<(3072 * 1024 / 4 + 255) / 256, 256, 0, stream>>>(Whh0, W0h, 3072 * 1024 / 4);
    cvt_bf16<<<(3072 * 1024 / 4 + 255) / 256, 256, 0, stream>>>(Wih1, W1i, 3072 * 1024 / 4);
    cvt_bf16<<<(3072 * 1024 / 4 + 255) / 256, 256, 0, stream>>>(Whh1, W1h, 3072 * 1024 / 4);
    cvt_bf16<<<(NB * SEQ * DIN0 / 4 + 255) / 256, 256, 0, stream>>>(x, xb, NB * SEQ * DIN0 / 4);
    init_h<<<512, 256, 0, stream>>>(h0, hf, hb);

    gru_persist<<<256, 512, 0, stream>>>(xb, W0i, W0h, W1i, W1h,
                                         bih0, bhh0, bih1, bhh1,
                                         hf, hb, out, bar);

    // both layers' t=511 state lands in parity 0
    hipMemcpyAsync(hnout,         hf,              65536 * sizeof(float),
                   hipMemcpyDeviceToDevice, stream);
    hipMemcpyAsync(hnout + 65536, hf + 2L * 65536, 65536 * sizeof(float),
                   hipMemcpyDeviceToDevice, stream);
}